// Round 1
// baseline (238.517 us; speedup 1.0000x reference)
//
#include <hip/hip_runtime.h>
#include <hip/hip_bf16.h>

#define HIDDEN 128
#define CAP 64

typedef __attribute__((ext_vector_type(8))) short bf16x8;
typedef __attribute__((ext_vector_type(4))) float f32x4;

__device__ __forceinline__ unsigned short f2bf(float f) {
    unsigned int u = __float_as_uint(f);
    u += 0x7FFFu + ((u >> 16) & 1u);   // round-to-nearest-even
    return (unsigned short)(u >> 16);
}

// Convert x (N*H floats) and W (H*H floats) to bf16 in one launch.
__global__ void convert_kernel(const float* __restrict__ x, const float* __restrict__ W,
                               unsigned short* __restrict__ xb, unsigned short* __restrict__ wb,
                               int nx4, int nw4) {
    int i = blockIdx.x * blockDim.x + threadIdx.x;
    if (i < nx4) {
        float4 v = ((const float4*)x)[i];
        ushort4 o;
        o.x = f2bf(v.x); o.y = f2bf(v.y); o.z = f2bf(v.z); o.w = f2bf(v.w);
        ((ushort4*)xb)[i] = o;
    } else {
        int j = i - nx4;
        if (j < nw4) {
            float4 v = ((const float4*)W)[j];
            ushort4 o;
            o.x = f2bf(v.x); o.y = f2bf(v.y); o.z = f2bf(v.z); o.w = f2bf(v.w);
            ((ushort4*)wb)[j] = o;
        }
    }
}

// Padded-CSR fill: one int atomic per edge. cnt doubles as in-degree.
__global__ void build_kernel(const int* __restrict__ ei, int E,
                             int* __restrict__ cnt, int* __restrict__ slots) {
    int e = blockIdx.x * blockDim.x + threadIdx.x;
    if (e >= E) return;
    int s = ei[e];          // src (row 0)
    int d = ei[E + e];      // dst (row 1)
    int slot = atomicAdd(&cnt[d], 1);
    if (slot < CAP) slots[d * CAP + slot] = s;
}

__global__ void dinv_kernel(const int* __restrict__ cnt, float* __restrict__ dinv, int n) {
    int i = blockIdx.x * blockDim.x + threadIdx.x;
    if (i < n) dinv[i] = rsqrtf((float)cnt[i]);
}

// C[r][c] = act( sum_k A[r][k] * Wb[c][k] + bias[c] )
// A: bf16 [nrows][128] row-major. Wb: bf16 [128][128] row-major ([c][k]).
// One wave computes a 16-row x 128-col strip via 8 col-tiles x 4 k-chunks.
template<bool GELU>
__global__ void gemm_kernel(const unsigned short* __restrict__ A,
                            const unsigned short* __restrict__ Wb,
                            const float* __restrict__ bias,
                            float* __restrict__ C, int nrows) {
    int lane = threadIdx.x & 63;
    int wave = threadIdx.x >> 6;
    int base = blockIdx.x * 64 + wave * 16;
    int hi = lane >> 4, lo = lane & 15;

    int arow = base + lo;
    if (arow >= nrows) arow = nrows - 1;          // clamp for tail loads
    const bf16x8* Ap = (const bf16x8*)(A + (size_t)arow * HIDDEN + hi * 8);

    f32x4 acc[8];
#pragma unroll
    for (int t = 0; t < 8; t++) acc[t] = (f32x4)(0.0f);

#pragma unroll
    for (int kk = 0; kk < 4; kk++) {
        bf16x8 a = Ap[kk * 4];                    // x[row][kk*32 + hi*8 .. +7]
#pragma unroll
        for (int t = 0; t < 8; t++) {
            const bf16x8* Bp = (const bf16x8*)(Wb + (size_t)(t * 16 + lo) * HIDDEN + kk * 32 + hi * 8);
            acc[t] = __builtin_amdgcn_mfma_f32_16x16x32_bf16(a, *Bp, acc[t], 0, 0, 0);
        }
    }

    // C/D layout: col = lane&15, row = (lane>>4)*4 + i   [measured m89/m91]
#pragma unroll
    for (int t = 0; t < 8; t++) {
        int col = t * 16 + lo;
        float bv = bias[col];
#pragma unroll
        for (int i = 0; i < 4; i++) {
            int r = base + hi * 4 + i;
            if (r < nrows) {
                float v = acc[t][i] + bv;
                if (GELU) v = 0.5f * v * (1.0f + erff(v * 0.70710678118f));
                C[(size_t)r * HIDDEN + col] = v;
            }
        }
    }
}

// One wave per node: gather h[src] rows, scale, accumulate f32, emit bf16.
__global__ void agg_kernel(const int* __restrict__ cnt, const int* __restrict__ slots,
                           const float* __restrict__ dinv, const float* __restrict__ h,
                           unsigned int* __restrict__ aggb, int n) {
    int lane = threadIdx.x & 63;
    int node = blockIdx.x * 4 + (threadIdx.x >> 6);
    if (node >= n) return;

    int degn = cnt[node];
    if (degn > CAP) degn = CAP;
    int s_l = slots[node * CAP + lane];            // always in-bounds read
    float dv_l = 0.0f;
    if (lane < degn) dv_l = dinv[s_l];             // guard: poison beyond degn
    float di = dinv[node];

    float accx = 0.0f, accy = 0.0f;
    for (int e = 0; e < degn; e++) {
        int s = __shfl(s_l, e);
        float f = __shfl(dv_l, e) * di;
        float2 hv = *(const float2*)(h + (size_t)s * HIDDEN + lane * 2);
        accx += f * hv.x;
        accy += f * hv.y;
    }
    aggb[(size_t)node * 64 + lane] =
        (unsigned int)f2bf(accx) | ((unsigned int)f2bf(accy) << 16);
}

extern "C" void kernel_launch(void* const* d_in, const int* in_sizes, int n_in,
                              void* d_out, int out_size, void* d_ws, size_t ws_size,
                              hipStream_t stream) {
    const float* x  = (const float*)d_in[0];
    const float* W  = (const float*)d_in[1];
    const float* b  = (const float*)d_in[2];
    const int*   ei = (const int*)d_in[3];

    int N = in_sizes[0] / HIDDEN;
    int E = in_sizes[3] / 2;

    char* ws = (char*)d_ws;
    size_t off = 0;
    int* cnt = (int*)(ws + off);               off += (((size_t)N * 4) + 255) & ~255ull;
    float* dinv = (float*)(ws + off);          off += (((size_t)N * 4) + 255) & ~255ull;
    int* slots = (int*)(ws + off);             off += (((size_t)N * CAP * 4) + 255) & ~255ull;
    unsigned short* xb = (unsigned short*)(ws + off);  off += (((size_t)N * HIDDEN * 2) + 255) & ~255ull;
    unsigned short* wb = (unsigned short*)(ws + off);  off += ((HIDDEN * HIDDEN * 2) + 255) & ~255ull;
    unsigned int* aggb = (unsigned int*)(ws + off);    off += (((size_t)N * HIDDEN * 2) + 255) & ~255ull;

    float* h = (float*)d_out;   // h scratch lives in d_out (overwritten by GEMM2)

    hipMemsetAsync(cnt, 0, (size_t)N * 4, stream);

    int nx4 = N * HIDDEN / 4, nw4 = HIDDEN * HIDDEN / 4;
    convert_kernel<<<(nx4 + nw4 + 255) / 256, 256, 0, stream>>>(x, W, xb, wb, nx4, nw4);
    build_kernel<<<(E + 255) / 256, 256, 0, stream>>>(ei, E, cnt, slots);
    dinv_kernel<<<(N + 255) / 256, 256, 0, stream>>>(cnt, dinv, N);
    gemm_kernel<false><<<(N + 63) / 64, 256, 0, stream>>>(xb, wb, b, h, N);
    agg_kernel<<<(N + 3) / 4, 256, 0, stream>>>(cnt, slots, dinv, h, aggb, N);
    gemm_kernel<true><<<(N + 63) / 64, 256, 0, stream>>>((unsigned short*)aggb, wb, b, (float*)d_out, N);
}

// Round 2
// 197.369 us; speedup vs baseline: 1.2085x; 1.2085x over previous
//
#include <hip/hip_runtime.h>
#include <hip/hip_bf16.h>

#define HIDDEN 128
#define CAP 64

typedef __attribute__((ext_vector_type(8))) short bf16x8;
typedef __attribute__((ext_vector_type(4))) float f32x4;

__device__ __forceinline__ unsigned short f2bf(float f) {
    unsigned int u = __float_as_uint(f);
    u += 0x7FFFu + ((u >> 16) & 1u);   // round-to-nearest-even
    return (unsigned short)(u >> 16);
}

__device__ __forceinline__ float bflo(unsigned int u) {  // low bf16 -> f32
    return __uint_as_float(u << 16);
}
__device__ __forceinline__ float bfhi(unsigned int u) {  // high bf16 -> f32
    return __uint_as_float(u & 0xffff0000u);
}

// Convert x (N*H floats) and W (H*H floats) to bf16 in one launch.
__global__ void convert_kernel(const float* __restrict__ x, const float* __restrict__ W,
                               unsigned short* __restrict__ xb, unsigned short* __restrict__ wb,
                               int nx4, int nw4) {
    int i = blockIdx.x * blockDim.x + threadIdx.x;
    if (i < nx4) {
        float4 v = ((const float4*)x)[i];
        ushort4 o;
        o.x = f2bf(v.x); o.y = f2bf(v.y); o.z = f2bf(v.z); o.w = f2bf(v.w);
        ((ushort4*)xb)[i] = o;
    } else {
        int j = i - nx4;
        if (j < nw4) {
            float4 v = ((const float4*)W)[j];
            ushort4 o;
            o.x = f2bf(v.x); o.y = f2bf(v.y); o.z = f2bf(v.z); o.w = f2bf(v.w);
            ((ushort4*)wb)[j] = o;
        }
    }
}

// Padded-CSR fill: one int atomic per edge. cnt doubles as in-degree.
__global__ void build_kernel(const int* __restrict__ ei, int E,
                             int* __restrict__ cnt, int* __restrict__ slots) {
    int e = blockIdx.x * blockDim.x + threadIdx.x;
    if (e >= E) return;
    int s = ei[e];          // src (row 0)
    int d = ei[E + e];      // dst (row 1)
    int slot = atomicAdd(&cnt[d], 1);
    if (slot < CAP) slots[d * CAP + slot] = s;
}

// y = A_norm * x  (bf16 gather, f32 accum, bf16 out) and c_i = sum_j n_ij.
// 16 lanes per node -> one dwordx4 gather instruction serves 4 edges.
__global__ void agg_kernel(const int* __restrict__ cnt, const int* __restrict__ slots,
                           const unsigned short* __restrict__ xb,
                           unsigned short* __restrict__ yb, float* __restrict__ cvec, int n) {
    int lane = threadIdx.x & 63;
    int wid  = threadIdx.x >> 6;
    int gl   = lane & 15;                      // lane within 16-lane group
    int node = blockIdx.x * 16 + wid * 4 + (lane >> 4);
    if (node >= n) return;                     // uniform per 16-lane group

    int deg_raw = cnt[node];
    int deg = deg_raw > CAP ? CAP : deg_raw;
    float di = rsqrtf((float)deg_raw);

    float acc[8];
#pragma unroll
    for (int k = 0; k < 8; k++) acc[k] = 0.0f;
    float fs = 0.0f;

    const int* srow = slots + (size_t)node * CAP;
    for (int be = 0; be < deg; be += 16) {
        int m = deg - be; if (m > 16) m = 16;
        int raw = srow[be + gl];
        int sidx = (gl < m) ? raw : 0;         // sanitize: poison slots -> node 0
        float dv = (gl < m) ? rsqrtf((float)cnt[sidx]) : 0.0f;
        for (int e = 0; e < m; e++) {
            int s = __shfl(sidx, e, 16);
            float f = __shfl(dv, e, 16) * di;
            fs += f;
            uint4 hv = *(const uint4*)(xb + (size_t)s * HIDDEN + gl * 8);
            acc[0] += f * bflo(hv.x); acc[1] += f * bfhi(hv.x);
            acc[2] += f * bflo(hv.y); acc[3] += f * bfhi(hv.y);
            acc[4] += f * bflo(hv.z); acc[5] += f * bfhi(hv.z);
            acc[6] += f * bflo(hv.w); acc[7] += f * bfhi(hv.w);
        }
    }

    uint4 o;
    o.x = (unsigned int)f2bf(acc[0]) | ((unsigned int)f2bf(acc[1]) << 16);
    o.y = (unsigned int)f2bf(acc[2]) | ((unsigned int)f2bf(acc[3]) << 16);
    o.z = (unsigned int)f2bf(acc[4]) | ((unsigned int)f2bf(acc[5]) << 16);
    o.w = (unsigned int)f2bf(acc[6]) | ((unsigned int)f2bf(acc[7]) << 16);
    *(uint4*)(yb + (size_t)node * HIDDEN + gl * 8) = o;
    if (gl == 0) cvec[node] = fs;
}

// Fused double GEMM: z = y*W^T + c.b ; out = gelu(z*W^T + b).
// One wave per 16-row strip; per-wave LDS transpose of z between the MFMAs.
__global__ void dgemm_kernel(const unsigned short* __restrict__ yb,
                             const unsigned short* __restrict__ wb,
                             const float* __restrict__ bias,
                             const float* __restrict__ cvec,
                             float* __restrict__ out, int nrows) {
    __shared__ unsigned short zs[4][16][136];   // +8 pad: 272B pitch -> 4-bank row shift
    int lane = threadIdx.x & 63;
    int wave = threadIdx.x >> 6;
    int base = blockIdx.x * 64 + wave * 16;
    int hi = lane >> 4, lo = lane & 15;

    int arow = base + lo;
    if (arow >= nrows) arow = nrows - 1;        // clamp for tail loads
    const bf16x8* Ap = (const bf16x8*)(yb + (size_t)arow * HIDDEN + hi * 8);

    f32x4 acc[8];
#pragma unroll
    for (int t = 0; t < 8; t++) acc[t] = (f32x4)(0.0f);

#pragma unroll
    for (int kk = 0; kk < 4; kk++) {
        bf16x8 a = Ap[kk * 4];
#pragma unroll
        for (int t = 0; t < 8; t++) {
            const bf16x8* Bp = (const bf16x8*)(wb + (size_t)(t * 16 + lo) * HIDDEN + kk * 32 + hi * 8);
            acc[t] = __builtin_amdgcn_mfma_f32_16x16x32_bf16(a, *Bp, acc[t], 0, 0, 0);
        }
    }

    // epilogue 1: z = acc + c*b  -> LDS (bf16), C-layout: row=hi*4+i, col=t*16+lo
    float cv[4];
#pragma unroll
    for (int i = 0; i < 4; i++) {
        int r = base + hi * 4 + i;
        cv[i] = cvec[r < nrows ? r : nrows - 1];
    }
#pragma unroll
    for (int t = 0; t < 8; t++) {
        float bv = bias[t * 16 + lo];
#pragma unroll
        for (int i = 0; i < 4; i++) {
            zs[wave][hi * 4 + i][t * 16 + lo] = f2bf(acc[t][i] + cv[i] * bv);
        }
    }
    __syncthreads();

    // second GEMM: out = gelu(z*W^T + b)
    f32x4 acc2[8];
#pragma unroll
    for (int t = 0; t < 8; t++) acc2[t] = (f32x4)(0.0f);
#pragma unroll
    for (int kk = 0; kk < 4; kk++) {
        bf16x8 a2 = *(const bf16x8*)&zs[wave][lo][kk * 32 + hi * 8];
#pragma unroll
        for (int t = 0; t < 8; t++) {
            const bf16x8* Bp = (const bf16x8*)(wb + (size_t)(t * 16 + lo) * HIDDEN + kk * 32 + hi * 8);
            acc2[t] = __builtin_amdgcn_mfma_f32_16x16x32_bf16(a2, *Bp, acc2[t], 0, 0, 0);
        }
    }
#pragma unroll
    for (int t = 0; t < 8; t++) {
        int col = t * 16 + lo;
        float bv = bias[col];
#pragma unroll
        for (int i = 0; i < 4; i++) {
            int r = base + hi * 4 + i;
            if (r < nrows) {
                float v = acc2[t][i] + bv;
                v = 0.5f * v * (1.0f + erff(v * 0.70710678118f));
                out[(size_t)r * HIDDEN + col] = v;
            }
        }
    }
}

extern "C" void kernel_launch(void* const* d_in, const int* in_sizes, int n_in,
                              void* d_out, int out_size, void* d_ws, size_t ws_size,
                              hipStream_t stream) {
    const float* x  = (const float*)d_in[0];
    const float* W  = (const float*)d_in[1];
    const float* b  = (const float*)d_in[2];
    const int*   ei = (const int*)d_in[3];

    int N = in_sizes[0] / HIDDEN;
    int E = in_sizes[3] / 2;

    char* ws = (char*)d_ws;
    size_t off = 0;
    int* cnt = (int*)(ws + off);               off += (((size_t)N * 4) + 255) & ~255ull;
    int* slots = (int*)(ws + off);             off += (((size_t)N * CAP * 4) + 255) & ~255ull;
    unsigned short* xb = (unsigned short*)(ws + off);  off += (((size_t)N * HIDDEN * 2) + 255) & ~255ull;
    unsigned short* wb = (unsigned short*)(ws + off);  off += ((HIDDEN * HIDDEN * 2) + 255) & ~255ull;
    unsigned short* yb = (unsigned short*)(ws + off);  off += (((size_t)N * HIDDEN * 2) + 255) & ~255ull;
    float* cvec = (float*)(ws + off);          off += (((size_t)N * 4) + 255) & ~255ull;

    hipMemsetAsync(cnt, 0, (size_t)N * 4, stream);

    int nx4 = N * HIDDEN / 4, nw4 = HIDDEN * HIDDEN / 4;
    convert_kernel<<<(nx4 + nw4 + 255) / 256, 256, 0, stream>>>(x, W, xb, wb, nx4, nw4);
    build_kernel<<<(E + 255) / 256, 256, 0, stream>>>(ei, E, cnt, slots);
    agg_kernel<<<(N + 15) / 16, 256, 0, stream>>>(cnt, slots, xb, yb, cvec, N);
    dgemm_kernel<<<(N + 63) / 64, 256, 0, stream>>>(yb, wb, b, cvec, (float*)d_out, N);
}